// Round 3
// baseline (1673.668 us; speedup 1.0000x reference)
//
#include <hip/hip_runtime.h>
#include <hip/hip_bf16.h>

typedef __hip_bfloat16 bf16;
typedef unsigned short u16;

static __device__ __forceinline__ float b2f(bf16 v) { return __bfloat162float(v); }

// ---------------- dtype detection ----------------
// f32 data -> low 16-bit halves have random bf16 exponents; bf16 N(0,1) never
// has exponent >= 0x8F (|v| >= 2^16). Wave-uniform flag for all later kernels.
__global__ void k_detect(const u16* __restrict__ xraw, int* __restrict__ flag) {
    __shared__ int s;
    if (threadIdx.x == 0) s = 0;
    __syncthreads();
    u16 u = xraw[threadIdx.x];
    int e = (u >> 7) & 0xFF;
    if (e >= 0x8F) atomicAdd(&s, 1);
    __syncthreads();
    if (threadIdx.x == 0) flag[0] = (s > 0) ? 1 : 0;
}

// ---------------- CSR build ----------------
__global__ void k_zero(int* __restrict__ cnt, int n) {
    int i = blockIdx.x * blockDim.x + threadIdx.x;
    if (i < n) cnt[i] = 0;
}

__global__ void k_count(const int* __restrict__ dst, int* __restrict__ cnt, int E) {
    int e = blockIdx.x * blockDim.x + threadIdx.x;
    if (e < E) atomicAdd(&cnt[dst[e]], 1);
}

// block b sums cnt[b*1024 .. b*1024+1023] -> partial[b]
__global__ void k_scan_partial(const int* __restrict__ cnt, int* __restrict__ partial, int n) {
    __shared__ int lds[256];
    int t = threadIdx.x;
    int base = blockIdx.x * 1024 + t * 4;
    int s = 0;
    #pragma unroll
    for (int k = 0; k < 4; k++) { int i = base + k; if (i < n) s += cnt[i]; }
    lds[t] = s; __syncthreads();
    for (int off = 128; off > 0; off >>= 1) {
        if (t < off) lds[t] += lds[t + off];
        __syncthreads();
    }
    if (t == 0) partial[blockIdx.x] = lds[0];
}

// single block (1024 threads): exclusive scan of partial[0..m) in place, m<=1024
__global__ void k_scan_block(int* __restrict__ partial, int m) {
    __shared__ int lds[1024];
    int t = threadIdx.x;
    int v = (t < m) ? partial[t] : 0;
    lds[t] = v; __syncthreads();
    for (int off = 1; off < 1024; off <<= 1) {
        int tmp = (t >= off) ? lds[t - off] : 0;
        __syncthreads();
        lds[t] += tmp;
        __syncthreads();
    }
    if (t < m) partial[t] = lds[t] - v;  // exclusive
}

// rowptr/cursor = global exclusive scan; dis = rsqrt(indeg+1)
__global__ void k_scan_final(const int* __restrict__ cnt, const int* __restrict__ partial,
                             int* __restrict__ rowptr, int* __restrict__ cursor,
                             float* __restrict__ dis, int n) {
    __shared__ int lds[256];
    int t = threadIdx.x;
    int base = blockIdx.x * 1024 + t * 4;
    int a[4]; int s = 0;
    #pragma unroll
    for (int k = 0; k < 4; k++) { int i = base + k; a[k] = (i < n) ? cnt[i] : 0; s += a[k]; }
    lds[t] = s; __syncthreads();
    for (int off = 1; off < 256; off <<= 1) {
        int tmp = (t >= off) ? lds[t - off] : 0;
        __syncthreads();
        lds[t] += tmp;
        __syncthreads();
    }
    int run = partial[blockIdx.x] + lds[t] - s;
    #pragma unroll
    for (int k = 0; k < 4; k++) {
        int i = base + k;
        if (i < n) {
            rowptr[i] = run; cursor[i] = run;
            dis[i] = rsqrtf((float)(a[k] + 1));
            run += a[k];
        }
    }
}

__global__ void k_fill(const int* __restrict__ src, const int* __restrict__ dst,
                       int* __restrict__ cursor, int* __restrict__ csr, int E) {
    int e = blockIdx.x * blockDim.x + threadIdx.x;
    if (e < E) {
        int pos = atomicAdd(&cursor[dst[e]], 1);
        csr[pos] = src[e];
    }
}

// ---------------- per-node matmul, pre-scaled by dis[v] ----------------
// g[v,:] = bf16( dis[v] * (in[row] @ W) )
template <int FIN, int FOUT, bool EXT>
__global__ void k_matmul(const void* __restrict__ xin, const int* __restrict__ gidx,
                         const bf16* __restrict__ actin,
                         const void* __restrict__ W, const float* __restrict__ dis,
                         bf16* __restrict__ g, const int* __restrict__ flag, int n) {
    __shared__ float Ws[FIN * FOUT];
    const int f32m = flag[0];
    for (int i = threadIdx.x; i < FIN * FOUT; i += blockDim.x)
        Ws[i] = f32m ? ((const float*)W)[i] : b2f(((const bf16*)W)[i]);
    __syncthreads();
    int v = blockIdx.x * blockDim.x + threadIdx.x;
    if (v >= n) return;

    float x[FIN];
    if (EXT) {
        if (f32m) {
            const float* p = (const float*)xin;
            #pragma unroll
            for (int k = 0; k < FIN; k++) x[k] = p[(size_t)v * FIN + k];
        } else {
            const bf16* p = (const bf16*)xin;
            #pragma unroll
            for (int k = 0; k < FIN; k++) x[k] = b2f(p[(size_t)v * FIN + k]);
        }
    } else {
        int row = gidx[v];
        #pragma unroll
        for (int k = 0; k < FIN; k++) x[k] = b2f(actin[(size_t)row * FIN + k]);
    }

    float y[FOUT];
    #pragma unroll
    for (int f = 0; f < FOUT; f++) y[f] = 0.f;
    #pragma unroll
    for (int k = 0; k < FIN; k++) {
        float xk = x[k];
        #pragma unroll
        for (int f = 0; f < FOUT; f++) y[f] = fmaf(xk, Ws[k * FOUT + f], y[f]);
    }

    float dv = dis[v];
    #pragma unroll
    for (int f = 0; f < FOUT; f++)
        g[(size_t)v * FOUT + f] = __float2bfloat16(dv * y[f]);
}

// ---------------- CSR gather + finalize ----------------
// act[v,f] = relu( dis[v] * (g[v,f] + sum_{u in N(v)} g[u,f]) + b[f] )
template <int FOUT>
__global__ void k_gather(const bf16* __restrict__ g, const int* __restrict__ rowptr,
                         const int* __restrict__ cnt, const int* __restrict__ csr,
                         const float* __restrict__ dis, const void* __restrict__ bias,
                         bf16* __restrict__ act, const int* __restrict__ flag, int total) {
    int i = blockIdx.x * blockDim.x + threadIdx.x;
    if (i >= total) return;
    int v = i / FOUT;
    int f = i - v * FOUT;
    float s = b2f(g[i]);  // self-loop term
    int r0 = rowptr[v], c = cnt[v];
    for (int j = 0; j < c; j++) {
        int u = csr[r0 + j];
        s += b2f(g[(size_t)u * FOUT + f]);
    }
    float bf = flag[0] ? ((const float*)bias)[f] : b2f(((const bf16*)bias)[f]);
    float val = fmaf(dis[v], s, bf);
    act[i] = __float2bfloat16(val > 0.f ? val : 0.f);
}

// ---------------- final unpool gather -> out (dtype per flag) ----------------
__global__ void k_gather_out(const bf16* __restrict__ act, const int* __restrict__ idx,
                             void* __restrict__ out, const int* __restrict__ flag, int n) {
    int u = blockIdx.x * blockDim.x + threadIdx.x;
    if (u >= n) return;
    size_t r = (size_t)idx[u];
    float v0 = b2f(act[3 * r + 0]);
    float v1 = b2f(act[3 * r + 1]);
    float v2 = b2f(act[3 * r + 2]);
    if (flag[0]) {
        float* o = (float*)out;
        o[3 * (size_t)u + 0] = v0; o[3 * (size_t)u + 1] = v1; o[3 * (size_t)u + 2] = v2;
    } else {
        bf16* o = (bf16*)out;
        o[3 * (size_t)u + 0] = __float2bfloat16(v0);
        o[3 * (size_t)u + 1] = __float2bfloat16(v1);
        o[3 * (size_t)u + 2] = __float2bfloat16(v2);
    }
}

// ---------------- host-side stage driver ----------------
struct Ws {
    int* flag; float* dis; int* cnt; int* rowptr; int* cursor; int* partial;
    int* csr; bf16* g; bf16* act;
};

static inline int cdiv(long long a, long long b) { return (int)((a + b - 1) / b); }

template <int FIN, int FOUT, bool EXT>
static void run_stage(const void* xin, const int* gidx, const bf16* actin,
                      const void* W, const void* bias,
                      const int* src, const int* dst, int E, int N,
                      const Ws& w, hipStream_t stream) {
    const int B = 256;
    int nScanBlocks = cdiv(N, 1024);
    k_zero<<<cdiv(N, B), B, 0, stream>>>(w.cnt, N);
    k_count<<<cdiv(E, B), B, 0, stream>>>(dst, w.cnt, E);
    k_scan_partial<<<nScanBlocks, B, 0, stream>>>(w.cnt, w.partial, N);
    k_scan_block<<<1, 1024, 0, stream>>>(w.partial, nScanBlocks);
    k_scan_final<<<nScanBlocks, B, 0, stream>>>(w.cnt, w.partial, w.rowptr, w.cursor, w.dis, N);
    k_fill<<<cdiv(E, B), B, 0, stream>>>(src, dst, w.cursor, w.csr, E);
    k_matmul<FIN, FOUT, EXT><<<cdiv(N, B), B, 0, stream>>>(xin, gidx, actin, W, w.dis, w.g, w.flag, N);
    k_gather<FOUT><<<cdiv((long long)N * FOUT, B), B, 0, stream>>>(
        w.g, w.rowptr, w.cnt, w.csr, w.dis, bias, w.act, w.flag, N * FOUT);
}

extern "C" void kernel_launch(void* const* d_in, const int* in_sizes, int n_in,
                              void* d_out, int out_size, void* d_ws, size_t ws_size,
                              hipStream_t stream) {
    const void* x  = d_in[0];
    const void* W1 = d_in[1]; const void* b1 = d_in[2];
    const void* W2 = d_in[3]; const void* b2 = d_in[4];
    const void* W3 = d_in[5]; const void* b3 = d_in[6];
    const void* W4 = d_in[7]; const void* b4 = d_in[8];
    const int* e0  = (const int*)d_in[9];
    const int* up1 = (const int*)d_in[10];
    const int* e1  = (const int*)d_in[11];
    const int* up2 = (const int*)d_in[12];
    const int* e2  = (const int*)d_in[13];
    const int* up3 = (const int*)d_in[14];
    const int* e3  = (const int*)d_in[15];
    const int* up4 = (const int*)d_in[16];

    const int N0 = in_sizes[0] / 3;
    const int N1 = in_sizes[10];
    const int N2 = in_sizes[12];
    const int N3 = in_sizes[14];
    const int N4 = in_sizes[16];
    const int E0 = in_sizes[9] / 2, E1 = in_sizes[11] / 2;
    const int E2 = in_sizes[13] / 2, E3 = in_sizes[15] / 2;

    // capacities
    size_t CAP = (size_t)N0 * 32;
    if ((size_t)N1 * 64 > CAP) CAP = (size_t)N1 * 64;
    if ((size_t)N2 * 32 > CAP) CAP = (size_t)N2 * 32;
    if ((size_t)N3 * 3  > CAP) CAP = (size_t)N3 * 3;
    size_t maxN = (size_t)(N3 > N2 ? N3 : N2);
    if ((size_t)N1 > maxN) maxN = N1;
    if ((size_t)N0 > maxN) maxN = N0;
    size_t maxE = (size_t)(E3 > E2 ? E3 : E2);
    if ((size_t)E1 > maxE) maxE = E1;
    if ((size_t)E0 > maxE) maxE = E0;
    size_t maxN4 = (maxN + 3) & ~(size_t)3;  // 16B-align successive arrays

    // workspace layout (~84 MB)
    char* p = (char*)d_ws;
    Ws w;
    w.flag    = (int*)p;            p += 256;
    w.dis     = (float*)p;          p += maxN4 * 4;
    w.cnt     = (int*)p;            p += maxN4 * 4;
    w.rowptr  = (int*)p;            p += maxN4 * 4;
    w.cursor  = (int*)p;            p += maxN4 * 4;
    w.partial = (int*)p;            p += 4096 * 4;
    w.csr     = (int*)p;            p += ((maxE + 3) & ~(size_t)3) * 4;
    w.g       = (bf16*)p;           p += ((CAP + 7) & ~(size_t)7) * 2;
    w.act     = (bf16*)p;           // CAP bf16

    const int B = 256;

    k_detect<<<1, 256, 0, stream>>>((const u16*)x, w.flag);

    // stage 1: x @ W1 -> 32, graph e0 (N0)
    run_stage<3, 32, true>(x, nullptr, nullptr, W1, b1, e0, e0 + E0, E0, N0, w, stream);
    // stage 2: act1[up1] @ W2 -> 64, graph e1 (N1)
    run_stage<32, 64, false>(nullptr, up1, w.act, W2, b2, e1, e1 + E1, E1, N1, w, stream);
    // stage 3: act2[up2] @ W3 -> 32, graph e2 (N2)
    run_stage<64, 32, false>(nullptr, up2, w.act, W3, b3, e2, e2 + E2, E2, N2, w, stream);
    // stage 4: act3[up3] @ W4 -> 3, graph e3 (N3)
    run_stage<32, 3, false>(nullptr, up3, w.act, W4, b4, e3, e3 + E3, E3, N3, w, stream);

    // final unpool
    k_gather_out<<<cdiv(N4, B), B, 0, stream>>>(w.act, up4, d_out, w.flag, N4);
}

// Round 4
// 1017.198 us; speedup vs baseline: 1.6454x; 1.6454x over previous
//
#include <hip/hip_runtime.h>
#include <hip/hip_bf16.h>

typedef __hip_bfloat16 bf16;
typedef unsigned short u16;
typedef unsigned int u32;

static __device__ __forceinline__ float b2f(bf16 v) { return __bfloat162float(v); }

#define TILE 8192   // edges per partition block

// ---------------- dtype detection ----------------
// f32 data -> low 16-bit halves have random bf16 exponents; bf16 N(0,1) never
// has exponent >= 0x8F (|v| >= 2^16). Wave-uniform flag for all later kernels.
__global__ void k_detect(const u16* __restrict__ xraw, int* __restrict__ flag) {
    __shared__ int s;
    if (threadIdx.x == 0) s = 0;
    __syncthreads();
    u16 u = xraw[threadIdx.x];
    int e = (u >> 7) & 0xFF;
    if (e >= 0x8F) atomicAdd(&s, 1);
    __syncthreads();
    if (threadIdx.x == 0) flag[0] = (s > 0) ? 1 : 0;
}

__global__ void k_zero(int* __restrict__ a, int n) {
    int i = blockIdx.x * blockDim.x + threadIdx.x;
    if (i < n) a[i] = 0;
}

// ---------------- pass A: partition edges into dst-range buckets ----------------
// pairs[bucket*cap + slot] = (local_dst << 21) | src   (src < 2^21, local < 2^11)
// Runs are block-reserved -> csr-pairs lines are (mostly) single-XCD.
__global__ void k_partition(const int* __restrict__ src, const int* __restrict__ dst,
                            int E, int bits, int cap,
                            int* __restrict__ gcursor, u32* __restrict__ pairs) {
    __shared__ int hist[512];
    __shared__ int cur[512];
    int t = threadIdx.x;
    for (int i = t; i < 512; i += 256) hist[i] = 0;
    __syncthreads();
    int e0 = blockIdx.x * TILE;
    int e1 = min(e0 + TILE, E);
    for (int e = e0 + t; e < e1; e += 256)
        atomicAdd(&hist[dst[e] >> bits], 1);
    __syncthreads();
    for (int b = t; b < 512; b += 256) {
        int h = hist[b];
        cur[b] = h ? atomicAdd(&gcursor[b], h) : 0;
    }
    __syncthreads();
    u32 mask = (1u << bits) - 1u;
    for (int e = e0 + t; e < e1; e += 256) {
        int d = dst[e];
        int b = d >> bits;
        int pos = atomicAdd(&cur[b], 1);
        pairs[(size_t)b * cap + pos] = (((u32)d & mask) << 21) | (u32)src[e];
    }
}

// ---------------- pass B1: per-bucket histogram -> cnt (coalesced writes) ----------------
__global__ void k_bucket_count(const u32* __restrict__ pairs, const int* __restrict__ gcursor,
                               int cap, int bits, int N, int* __restrict__ cnt) {
    __shared__ int hist[2048];
    int b = blockIdx.x, t = threadIdx.x;
    int range = 1 << bits;
    for (int i = t; i < range; i += 256) hist[i] = 0;
    __syncthreads();
    int n = gcursor[b];
    const u32* p = pairs + (size_t)b * cap;
    for (int i = t; i < n; i += 256)
        atomicAdd(&hist[p[i] >> 21], 1);
    __syncthreads();
    int base = b << bits;
    for (int i = t; i < range; i += 256) {
        int v = base + i;
        if (v < N) cnt[v] = hist[i];
    }
}

// ---------------- global exclusive scan of cnt -> rowptr (+dis) ----------------
__global__ void k_scan_partial(const int* __restrict__ cnt, int* __restrict__ partial, int n) {
    __shared__ int lds[256];
    int t = threadIdx.x;
    int base = blockIdx.x * 1024 + t * 4;
    int s = 0;
    #pragma unroll
    for (int k = 0; k < 4; k++) { int i = base + k; if (i < n) s += cnt[i]; }
    lds[t] = s; __syncthreads();
    for (int off = 128; off > 0; off >>= 1) {
        if (t < off) lds[t] += lds[t + off];
        __syncthreads();
    }
    if (t == 0) partial[blockIdx.x] = lds[0];
}

__global__ void k_scan_block(int* __restrict__ partial, int m) {
    __shared__ int lds[1024];
    int t = threadIdx.x;
    int v = (t < m) ? partial[t] : 0;
    lds[t] = v; __syncthreads();
    for (int off = 1; off < 1024; off <<= 1) {
        int tmp = (t >= off) ? lds[t - off] : 0;
        __syncthreads();
        lds[t] += tmp;
        __syncthreads();
    }
    if (t < m) partial[t] = lds[t] - v;  // exclusive
}

__global__ void k_scan_final(const int* __restrict__ cnt, const int* __restrict__ partial,
                             int* __restrict__ rowptr, float* __restrict__ dis, int n) {
    __shared__ int lds[256];
    int t = threadIdx.x;
    int base = blockIdx.x * 1024 + t * 4;
    int a[4]; int s = 0;
    #pragma unroll
    for (int k = 0; k < 4; k++) { int i = base + k; a[k] = (i < n) ? cnt[i] : 0; s += a[k]; }
    lds[t] = s; __syncthreads();
    for (int off = 1; off < 256; off <<= 1) {
        int tmp = (t >= off) ? lds[t - off] : 0;
        __syncthreads();
        lds[t] += tmp;
        __syncthreads();
    }
    int run = partial[blockIdx.x] + lds[t] - s;
    #pragma unroll
    for (int k = 0; k < 4; k++) {
        int i = base + k;
        if (i < n) {
            rowptr[i] = run;
            dis[i] = rsqrtf((float)(a[k] + 1));
            run += a[k];
        }
    }
}

// ---------------- pass B2: per-bucket scatter into contiguous csr span ----------------
__global__ void k_bucket_fill(const u32* __restrict__ pairs, const int* __restrict__ gcursor,
                              int cap, int bits, int N, const int* __restrict__ rowptr,
                              int* __restrict__ csr) {
    __shared__ int cur[2048];
    int b = blockIdx.x, t = threadIdx.x;
    int range = 1 << bits;
    int base = b << bits;
    for (int i = t; i < range; i += 256) {
        int v = base + i;
        cur[i] = (v < N) ? rowptr[v] : 0;
    }
    __syncthreads();
    int n = gcursor[b];
    const u32* p = pairs + (size_t)b * cap;
    for (int i = t; i < n; i += 256) {
        u32 u = p[i];
        int pos = atomicAdd(&cur[u >> 21], 1);
        csr[pos] = (int)(u & 0x1FFFFFu);
    }
}

// ---------------- per-node matmul, pre-scaled by dis[v] ----------------
// g[v,:] = bf16( dis[v] * (in[row] @ W) )
template <int FIN, int FOUT, bool EXT>
__global__ void k_matmul(const void* __restrict__ xin, const int* __restrict__ gidx,
                         const bf16* __restrict__ actin,
                         const void* __restrict__ W, const float* __restrict__ dis,
                         bf16* __restrict__ g, const int* __restrict__ flag, int n) {
    __shared__ float Ws[FIN * FOUT];
    const int f32m = flag[0];
    for (int i = threadIdx.x; i < FIN * FOUT; i += blockDim.x)
        Ws[i] = f32m ? ((const float*)W)[i] : b2f(((const bf16*)W)[i]);
    __syncthreads();
    int v = blockIdx.x * blockDim.x + threadIdx.x;
    if (v >= n) return;

    float x[FIN];
    if (EXT) {
        if (f32m) {
            const float* p = (const float*)xin;
            #pragma unroll
            for (int k = 0; k < FIN; k++) x[k] = p[(size_t)v * FIN + k];
        } else {
            const bf16* p = (const bf16*)xin;
            #pragma unroll
            for (int k = 0; k < FIN; k++) x[k] = b2f(p[(size_t)v * FIN + k]);
        }
    } else {
        int row = gidx[v];
        #pragma unroll
        for (int k = 0; k < FIN; k++) x[k] = b2f(actin[(size_t)row * FIN + k]);
    }

    float y[FOUT];
    #pragma unroll
    for (int f = 0; f < FOUT; f++) y[f] = 0.f;
    #pragma unroll
    for (int k = 0; k < FIN; k++) {
        float xk = x[k];
        #pragma unroll
        for (int f = 0; f < FOUT; f++) y[f] = fmaf(xk, Ws[k * FOUT + f], y[f]);
    }

    float dv = dis[v];
    #pragma unroll
    for (int f = 0; f < FOUT; f++)
        g[(size_t)v * FOUT + f] = __float2bfloat16(dv * y[f]);
}

// ---------------- CSR gather + finalize ----------------
// act[v,f] = relu( dis[v] * (g[v,f] + sum_{u in N(v)} g[u,f]) + b[f] )
template <int FOUT>
__global__ void k_gather(const bf16* __restrict__ g, const int* __restrict__ rowptr,
                         const int* __restrict__ cnt, const int* __restrict__ csr,
                         const float* __restrict__ dis, const void* __restrict__ bias,
                         bf16* __restrict__ act, const int* __restrict__ flag, int total) {
    int i = blockIdx.x * blockDim.x + threadIdx.x;
    if (i >= total) return;
    int v = i / FOUT;
    int f = i - v * FOUT;
    float s = b2f(g[i]);  // self-loop term
    int r0 = rowptr[v], c = cnt[v];
    for (int j = 0; j < c; j++) {
        int u = csr[r0 + j];
        s += b2f(g[(size_t)u * FOUT + f]);
    }
    float bf = flag[0] ? ((const float*)bias)[f] : b2f(((const bf16*)bias)[f]);
    float val = fmaf(dis[v], s, bf);
    act[i] = __float2bfloat16(val > 0.f ? val : 0.f);
}

// ---------------- final unpool gather -> out (dtype per flag) ----------------
__global__ void k_gather_out(const bf16* __restrict__ act, const int* __restrict__ idx,
                             void* __restrict__ out, const int* __restrict__ flag, int n) {
    int u = blockIdx.x * blockDim.x + threadIdx.x;
    if (u >= n) return;
    size_t r = (size_t)idx[u];
    float v0 = b2f(act[3 * r + 0]);
    float v1 = b2f(act[3 * r + 1]);
    float v2 = b2f(act[3 * r + 2]);
    if (flag[0]) {
        float* o = (float*)out;
        o[3 * (size_t)u + 0] = v0; o[3 * (size_t)u + 1] = v1; o[3 * (size_t)u + 2] = v2;
    } else {
        bf16* o = (bf16*)out;
        o[3 * (size_t)u + 0] = __float2bfloat16(v0);
        o[3 * (size_t)u + 1] = __float2bfloat16(v1);
        o[3 * (size_t)u + 2] = __float2bfloat16(v2);
    }
}

// ---------------- host-side stage driver ----------------
struct Ws {
    int* flag; float* dis; int* cnt; int* rowptr; int* partial; int* gcursor;
    int* csr; u32* pairs; bf16* g; /* g aliases pairs */ bf16* act;
};

static inline int cdiv(long long a, long long b) { return (int)((a + b - 1) / b); }

static inline int range_bits_for(int N) {
    int bits = 8;
    while (cdiv(N, 1 << bits) > 512) bits++;
    return bits;
}

template <int FIN, int FOUT, bool EXT>
static void run_stage(const void* xin, const int* gidx, const bf16* actin,
                      const void* W, const void* bias,
                      const int* src, const int* dst, int E, int N,
                      const Ws& w, hipStream_t stream) {
    const int B = 256;
    int bits = range_bits_for(N);
    int nb = cdiv(N, 1 << bits);
    int cap = E / nb + E / (4 * nb) + 256;
    int nScanBlocks = cdiv(N, 1024);

    k_zero<<<1, 512, 0, stream>>>(w.gcursor, 512);
    k_partition<<<cdiv(E, TILE), B, 0, stream>>>(src, dst, E, bits, cap, w.gcursor, w.pairs);
    k_bucket_count<<<nb, B, 0, stream>>>(w.pairs, w.gcursor, cap, bits, N, w.cnt);
    k_scan_partial<<<nScanBlocks, B, 0, stream>>>(w.cnt, w.partial, N);
    k_scan_block<<<1, 1024, 0, stream>>>(w.partial, nScanBlocks);
    k_scan_final<<<nScanBlocks, B, 0, stream>>>(w.cnt, w.partial, w.rowptr, w.dis, N);
    k_bucket_fill<<<nb, B, 0, stream>>>(w.pairs, w.gcursor, cap, bits, N, w.rowptr, w.csr);
    // g aliases pairs: pairs dead after k_bucket_fill
    k_matmul<FIN, FOUT, EXT><<<cdiv(N, B), B, 0, stream>>>(xin, gidx, actin, W, w.dis, w.g, w.flag, N);
    k_gather<FOUT><<<cdiv((long long)N * FOUT, B), B, 0, stream>>>(
        w.g, w.rowptr, w.cnt, w.csr, w.dis, bias, w.act, w.flag, N * FOUT);
}

extern "C" void kernel_launch(void* const* d_in, const int* in_sizes, int n_in,
                              void* d_out, int out_size, void* d_ws, size_t ws_size,
                              hipStream_t stream) {
    const void* x  = d_in[0];
    const void* W1 = d_in[1]; const void* b1 = d_in[2];
    const void* W2 = d_in[3]; const void* b2 = d_in[4];
    const void* W3 = d_in[5]; const void* b3 = d_in[6];
    const void* W4 = d_in[7]; const void* b4 = d_in[8];
    const int* e0  = (const int*)d_in[9];
    const int* up1 = (const int*)d_in[10];
    const int* e1  = (const int*)d_in[11];
    const int* up2 = (const int*)d_in[12];
    const int* e2  = (const int*)d_in[13];
    const int* up3 = (const int*)d_in[14];
    const int* e3  = (const int*)d_in[15];
    const int* up4 = (const int*)d_in[16];

    const int N0 = in_sizes[0] / 3;
    const int N1 = in_sizes[10];
    const int N2 = in_sizes[12];
    const int N3 = in_sizes[14];
    const int N4 = in_sizes[16];
    const int E0 = in_sizes[9] / 2, E1 = in_sizes[11] / 2;
    const int E2 = in_sizes[13] / 2, E3 = in_sizes[15] / 2;

    // capacities
    size_t CAP = (size_t)N0 * 32;
    if ((size_t)N1 * 64 > CAP) CAP = (size_t)N1 * 64;
    if ((size_t)N2 * 32 > CAP) CAP = (size_t)N2 * 32;
    if ((size_t)N3 * 3  > CAP) CAP = (size_t)N3 * 3;
    size_t maxN = (size_t)(N3 > N2 ? N3 : N2);
    if ((size_t)N1 > maxN) maxN = N1;
    if ((size_t)N0 > maxN) maxN = N0;
    size_t maxE = (size_t)(E3 > E2 ? E3 : E2);
    if ((size_t)E1 > maxE) maxE = E1;
    if ((size_t)E0 > maxE) maxE = E0;
    size_t maxN4 = (maxN + 3) & ~(size_t)3;

    // max pairs capacity over stages
    size_t maxPairs = 0;
    {
        int Ns[4] = {N0, N1, N2, N3};
        int Es[4] = {E0, E1, E2, E3};
        for (int s = 0; s < 4; s++) {
            int bits = range_bits_for(Ns[s]);
            int nb = cdiv(Ns[s], 1 << bits);
            size_t cap = (size_t)(Es[s] / nb + Es[s] / (4 * nb) + 256);
            size_t tot = cap * (size_t)nb;
            if (tot > maxPairs) maxPairs = tot;
        }
    }

    // workspace layout (~80 MB): pairs/g share a union region
    size_t uBytes = maxPairs * 4;
    if (CAP * 2 > uBytes) uBytes = CAP * 2;
    uBytes = (uBytes + 255) & ~(size_t)255;

    char* p = (char*)d_ws;
    Ws w;
    w.flag    = (int*)p;            p += 256;
    w.dis     = (float*)p;          p += maxN4 * 4;
    w.cnt     = (int*)p;            p += maxN4 * 4;
    w.rowptr  = (int*)p;            p += maxN4 * 4;
    w.partial = (int*)p;            p += 4096 * 4;
    w.gcursor = (int*)p;            p += 1024 * 4;
    w.csr     = (int*)p;            p += ((maxE + 3) & ~(size_t)3) * 4;
    w.pairs   = (u32*)p;
    w.g       = (bf16*)p;           p += uBytes;
    w.act     = (bf16*)p;           // CAP bf16

    const int B = 256;

    k_detect<<<1, 256, 0, stream>>>((const u16*)x, w.flag);

    // stage 1: x @ W1 -> 32, graph e0 (N0)
    run_stage<3, 32, true>(x, nullptr, nullptr, W1, b1, e0, e0 + E0, E0, N0, w, stream);
    // stage 2: act1[up1] @ W2 -> 64, graph e1 (N1)
    run_stage<32, 64, false>(nullptr, up1, w.act, W2, b2, e1, e1 + E1, E1, N1, w, stream);
    // stage 3: act2[up2] @ W3 -> 32, graph e2 (N2)
    run_stage<64, 32, false>(nullptr, up2, w.act, W3, b3, e2, e2 + E2, E2, N2, w, stream);
    // stage 4: act3[up3] @ W4 -> 3, graph e3 (N3)
    run_stage<32, 3, false>(nullptr, up3, w.act, W4, b4, e3, e3 + E3, E3, N3, w, stream);

    // final unpool
    k_gather_out<<<cdiv(N4, B), B, 0, stream>>>(w.act, up4, d_out, w.flag, N4);
}